// Round 1
// 145.316 us; speedup vs baseline: 1.0238x; 1.0238x over previous
//
#include <hip/hip_runtime.h>
#include <math.h>

#define NB 32     // batch
#define NS 1024   // seq len
#define NT 64     // turns
#define ENC 768   // encoder dim

// Single fused kernel: one block per batch.
//   Phase 1 (16 waves): e[t] = dot(encoder[b, ids[b,t], :], w_e)  for t=0..63 -> LDS
//   Phase 2 (wave 0):   wave-parallel suffix-logsumexp over valid turns,
//                       loss_b = sum_{k=1..L-1} (M + log(S_k) - e[k]),
//                       cnt    = sum_b (L_b - 1)   (computed identically by every block),
//                       atomicAdd(out, loss_b / cnt)   (out pre-zeroed by memset).
// No d_ws usage, no inter-kernel round-trip, no serial 62-step exp/log chain.
__global__ __launch_bounds__(1024) void fused_loss_kernel(
    const float* __restrict__ enc,
    const float* __restrict__ fc_w,
    const int* __restrict__ ids,
    const int* __restrict__ tlen,
    float* __restrict__ out)
{
    __shared__ float e_s[NT];
    const int b    = blockIdx.x;
    const int wave = threadIdx.x >> 6;   // 0..15
    const int lane = threadIdx.x & 63;

    // w_e = fc_w[0, 256:1024]; 12 floats per lane, reused for 4 rows.
    const float* we = fc_w + 256;
    const float4 w0 = *(const float4*)(we + (0 * 64 + lane) * 4);
    const float4 w1 = *(const float4*)(we + (1 * 64 + lane) * 4);
    const float4 w2 = *(const float4*)(we + (2 * 64 + lane) * 4);

    const float* encb = enc + (size_t)b * NS * ENC;
    const int*   idsb = ids + b * NT;

    // 4 rows per wave: issue all 12 global loads (12 KB/wave in flight),
    // then do the 4 reduces. ~48+12 VGPRs of data, fits the 128-VGPR
    // budget that a 1024-thread block requires (16 waves/CU).
    float4 x[4][3];
#pragma unroll
    for (int r = 0; r < 4; ++r) {
        const int t = wave * 4 + r;
        const float* row = encb + (size_t)idsb[t] * ENC;
        x[r][0] = *(const float4*)(row + (0 * 64 + lane) * 4);
        x[r][1] = *(const float4*)(row + (1 * 64 + lane) * 4);
        x[r][2] = *(const float4*)(row + (2 * 64 + lane) * 4);
    }
#pragma unroll
    for (int r = 0; r < 4; ++r) {
        float s = x[r][0].x * w0.x + x[r][0].y * w0.y + x[r][0].z * w0.z + x[r][0].w * w0.w
                + x[r][1].x * w1.x + x[r][1].y * w1.y + x[r][1].z * w1.z + x[r][1].w * w1.w
                + x[r][2].x * w2.x + x[r][2].y * w2.y + x[r][2].z * w2.z + x[r][2].w * w2.w;
#pragma unroll
        for (int sh = 32; sh > 0; sh >>= 1) s += __shfl_xor(s, sh, 64);
        if (lane == 0) e_s[wave * 4 + r] = s;
    }
    __syncthreads();
    if (wave != 0) return;

    // ---- wave 0: parallel suffix-logsumexp, lane t <-> turn t ----
    const int L = tlen[b];                       // L in [2, 64]
    const int t = lane;
    const bool valid = (t >= 1) && (t < L);      // loss terms use k in [1, L-1]
    const float e_t = e_s[t];
    float v = valid ? e_t : -INFINITY;

    // global max over valid turns (L>=2 guarantees at least lane 1 is valid)
    float M = v;
#pragma unroll
    for (int sh = 32; sh > 0; sh >>= 1) M = fmaxf(M, __shfl_xor(M, sh, 64));

    float ex = valid ? expf(e_t - M) : 0.f;

    // inclusive suffix sum: S_t = sum_{j >= t} ex_j
    float S = ex;
#pragma unroll
    for (int sh = 1; sh < 64; sh <<= 1) {
        const float o = __shfl_down(S, sh, 64);
        if (lane + sh < 64) S += o;
    }

    float loss = valid ? (M + logf(S) - e_t) : 0.f;
#pragma unroll
    for (int sh = 32; sh > 0; sh >>= 1) loss += __shfl_xor(loss, sh, 64);

    // global denominator: every block computes the same sum over all batches
    float c = (lane < NB) ? (float)(tlen[lane] - 1) : 0.f;
#pragma unroll
    for (int sh = 32; sh > 0; sh >>= 1) c += __shfl_xor(c, sh, 64);

    if (lane == 0) atomicAdd(out, loss / c);
}

extern "C" void kernel_launch(void* const* d_in, const int* in_sizes, int n_in,
                              void* d_out, int out_size, void* d_ws, size_t ws_size,
                              hipStream_t stream) {
    // Inputs (setup_inputs order):
    // 0 encoder_output (B,S,ENC) f32 | 1 W_ih | 2 W_hh | 3 b_ih | 4 b_hh
    // 5 fc_w (1,1024) f32 | 6 fc_b | 7 his_turn_end_ids (B,T) i32 | 8 turn_lengths (B,) i32
    // The LSTM path (1,2,3,4, fc_w[:256], fc_b) cancels out of the loss algebraically.
    const float* enc  = (const float*)d_in[0];
    const float* fc_w = (const float*)d_in[5];
    const int*   ids  = (const int*)d_in[7];
    const int*   tlen = (const int*)d_in[8];

    hipMemsetAsync(d_out, 0, sizeof(float), stream);   // accumulator for 32 atomicAdds
    fused_loss_kernel<<<NB, 1024, 0, stream>>>(enc, fc_w, ids, tlen, (float*)d_out);
}